// Round 1
// baseline (643.337 us; speedup 1.0000x reference)
//
#include <hip/hip_runtime.h>

// Problem constants
#define Bv 32
#define Tv 2048
#define Hv 512
#define Dv 1024

using bf16x8 = __attribute__((ext_vector_type(8))) __bf16;
using bf16x4 = __attribute__((ext_vector_type(4))) __bf16;
using f32x4  = __attribute__((ext_vector_type(4))) float;

// ---------------------------------------------------------------------------
// Kernel 1 (fused prep): one block per h row.
//  (a) We = W_attn[h, D:2D] -> bf16 MFMA B-fragment order (threads 0..127)
//  (b) hp[b][h] = hidden[b,:] . W_attn[h,0:D] + b_attn[h]   (all 256 threads)
// ---------------------------------------------------------------------------
__global__ void prep_kernel(const float* __restrict__ hidden,
                            const float* __restrict__ W,
                            const float* __restrict__ b_attn,
                            bf16x8* __restrict__ We_sw,
                            float* __restrict__ hp) {
    int h   = blockIdx.x;            // 0..511
    int tid = threadIdx.x;           // 256

    // --- (a) swizzle We row h ---
    if (tid < 128) {
        int d = tid * 8;
        const float* src = W + h * (2 * Dv) + Dv + d;
        float4 f0 = *(const float4*)src;
        float4 f1 = *(const float4*)(src + 4);
        bf16x8 o;
        o[0] = (__bf16)f0.x; o[1] = (__bf16)f0.y; o[2] = (__bf16)f0.z; o[3] = (__bf16)f0.w;
        o[4] = (__bf16)f1.x; o[5] = (__bf16)f1.y; o[6] = (__bf16)f1.z; o[7] = (__bf16)f1.w;
        int s = ((h >> 4) * 32 + (d >> 5)) * 64 + (((d >> 3) & 3) << 4) + (h & 15);
        We_sw[s] = o;
    }

    // --- (b) hid_proj ---
    float4 wh = ((const float4*)(W + h * (2 * Dv)))[tid];
    __shared__ float red[4][Bv];
    int lane = tid & 63, w = tid >> 6;
    for (int b = 0; b < Bv; ++b) {
        float4 x = ((const float4*)(hidden + b * Dv))[tid];
        float p = wh.x * x.x + wh.y * x.y + wh.z * x.z + wh.w * x.w;
#pragma unroll
        for (int m = 1; m < 64; m <<= 1) p += __shfl_xor(p, m);
        if (lane == 0) red[w][b] = p;
    }
    __syncthreads();
    if (tid < Bv)
        hp[tid * Hv + h] = red[0][tid] + red[1][tid] + red[2][tid] + red[3][tid] + b_attn[h];
}

__device__ __forceinline__ float fast_tanh(float x) {
    float xc = fminf(fmaxf(x, -9.0f), 9.0f);
    float e  = __expf(2.0f * xc);
    return 1.0f - 2.0f / (e + 1.0f);
}

// ---------------------------------------------------------------------------
// Kernel 2: scores[b,t] = sum_h v[h]*tanh( enc[b,t,:].We[h,:] + hp[b,h] )
// Persistent: 256 blocks, each owns 4 consecutive 64-row tiles.
//   - K-chunk = 128 floats (8 chunks/tile, 8 barriers/tile instead of 16)
//   - A(chunk+1) issued before barrier; A(tile+1, chunk0) issued during the
//     last chunk of the current tile (prologue latency hidden 3 of 4 times)
//   - B fragments rolling-prefetched one half-chunk (64 k) ahead; next tile's
//     first B pair loaded before the epilogue so L2 latency hides under it.
// LDS: row-major 64 x 136 bf16 (272 B row stride, 16B-aligned b128 reads,
// 2-way-max read conflicts = free), double buffered.
// ---------------------------------------------------------------------------
__global__ __launch_bounds__(512) void attn_main(
    const float* __restrict__ enc, const bf16x8* __restrict__ Bg,
    const float* __restrict__ hp, const float* __restrict__ vvec,
    float* __restrict__ scores)
{
    __shared__ __align__(16) __bf16 Abuf[2][64 * 136];  // 2 x 17408 B
    __shared__ float redbuf[8][64];

    const int tid  = threadIdx.x;
    const int lane = tid & 63;
    const int w    = tid >> 6;           // wave 0..7

    // --- A staging map: thread -> row = tid>>3, col segs (tid&7)*4 + s*32
    const int srow = tid >> 3;           // 0..63
    const int sd0  = (tid & 7) * 4;      // 0,4,..,28
    __bf16* lw0 = &Abuf[0][srow * 136 + sd0];

    // --- B fragment base: frag(j,kt) at Bg[((w*4+j)*32 + kt)*64 + lane]
    const bf16x8* Bptr = Bg + (w * 4 * 32) * 64 + lane;

    const int arow  = lane & 15;
    const int acol8 = (lane >> 4) * 8;

    const int row0 = blockIdx.x * 256;   // 4 tiles of 64 rows

    // prologue: A(tile0, chunk0) and B(kt=0,1)
    float4 f[4];
    {
        const float* gA = enc + (row0 + srow) * Dv + sd0;
#pragma unroll
        for (int s = 0; s < 4; ++s) f[s] = *(const float4*)(gA + s * 32);
    }
    bf16x8 Bc[2][4];
#pragma unroll
    for (int ktl = 0; ktl < 2; ++ktl)
#pragma unroll
        for (int j = 0; j < 4; ++j)
            Bc[ktl][j] = Bptr[(j * 32 + ktl) * 64];

    for (int tile = 0; tile < 4; ++tile) {
        const int trow0  = row0 + tile * 64;
        const int batch  = trow0 >> 11;
        const float* gAt = enc + (trow0 + srow) * Dv + sd0;

        f32x4 acc[4][4];
#pragma unroll
        for (int i = 0; i < 4; ++i)
#pragma unroll
            for (int j = 0; j < 4; ++j)
                acc[i][j] = (f32x4){0.f, 0.f, 0.f, 0.f};

        for (int kc = 0; kc < 8; ++kc) {
            // convert + store A(kc) into buf kc&1
            __bf16* p = lw0 + (kc & 1) * (64 * 136);
#pragma unroll
            for (int s = 0; s < 4; ++s) {
                bf16x4 o;
                o[0] = (__bf16)f[s].x; o[1] = (__bf16)f[s].y;
                o[2] = (__bf16)f[s].z; o[3] = (__bf16)f[s].w;
                *(bf16x4*)(p + s * 32) = o;
            }
            // issue next A loads: next chunk, or next tile's chunk 0
            if (kc < 7) {
#pragma unroll
                for (int s = 0; s < 4; ++s)
                    f[s] = *(const float4*)(gAt + (kc + 1) * 128 + s * 32);
            } else if (tile < 3) {
                const float* gAn = enc + (trow0 + 64 + srow) * Dv + sd0;
#pragma unroll
                for (int s = 0; s < 4; ++s)
                    f[s] = *(const float4*)(gAn + s * 32);
            }
            __syncthreads();

            const __bf16* rb = &Abuf[kc & 1][0];
#pragma unroll
            for (int hk = 0; hk < 2; ++hk) {
                // rolling B prefetch one half-chunk (64 k) ahead
                bf16x8 Bn[2][4];
                const int ktn = kc * 4 + (hk + 1) * 2;
                if (ktn < 32) {
#pragma unroll
                    for (int ktl = 0; ktl < 2; ++ktl)
#pragma unroll
                        for (int j = 0; j < 4; ++j)
                            Bn[ktl][j] = Bptr[(j * 32 + ktn + ktl) * 64];
                }
#pragma unroll
                for (int ktl = 0; ktl < 2; ++ktl) {
                    const int kofs = (hk * 2 + ktl) * 32;
                    bf16x8 a0 = *(const bf16x8*)(rb + (0 * 16 + arow) * 136 + kofs + acol8);
                    bf16x8 a1 = *(const bf16x8*)(rb + (1 * 16 + arow) * 136 + kofs + acol8);
                    bf16x8 a2 = *(const bf16x8*)(rb + (2 * 16 + arow) * 136 + kofs + acol8);
                    bf16x8 a3 = *(const bf16x8*)(rb + (3 * 16 + arow) * 136 + kofs + acol8);
#pragma unroll
                    for (int j = 0; j < 4; ++j) {
                        acc[0][j] = __builtin_amdgcn_mfma_f32_16x16x32_bf16(a0, Bc[ktl][j], acc[0][j], 0, 0, 0);
                        acc[1][j] = __builtin_amdgcn_mfma_f32_16x16x32_bf16(a1, Bc[ktl][j], acc[1][j], 0, 0, 0);
                        acc[2][j] = __builtin_amdgcn_mfma_f32_16x16x32_bf16(a2, Bc[ktl][j], acc[2][j], 0, 0, 0);
                        acc[3][j] = __builtin_amdgcn_mfma_f32_16x16x32_bf16(a3, Bc[ktl][j], acc[3][j], 0, 0, 0);
                    }
                }
                if (ktn < 32) {
#pragma unroll
                    for (int ktl = 0; ktl < 2; ++ktl)
#pragma unroll
                        for (int j = 0; j < 4; ++j)
                            Bc[ktl][j] = Bn[ktl][j];
                }
            }
        }

        // preload next tile's first B pair: L2 latency hides under epilogue
        if (tile < 3) {
#pragma unroll
            for (int ktl = 0; ktl < 2; ++ktl)
#pragma unroll
                for (int j = 0; j < 4; ++j)
                    Bc[ktl][j] = Bptr[(j * 32 + ktl) * 64];
        }

        // Epilogue. C/D layout: col = lane&15, row = (lane>>4)*4 + reg
        float hpv[4], vv[4];
#pragma unroll
        for (int j = 0; j < 4; ++j) {
            int n  = w * 64 + j * 16 + (lane & 15);
            hpv[j] = hp[batch * Hv + n];
            vv[j]  = vvec[n];
        }
        const int qrow = (lane >> 4) * 4;
#pragma unroll
        for (int mt = 0; mt < 4; ++mt)
#pragma unroll
            for (int r = 0; r < 4; ++r) {
                float p = 0.f;
#pragma unroll
                for (int j = 0; j < 4; ++j)
                    p += vv[j] * fast_tanh(acc[mt][j][r] + hpv[j]);
                p += __shfl_xor(p, 1);
                p += __shfl_xor(p, 2);
                p += __shfl_xor(p, 4);
                p += __shfl_xor(p, 8);
                if ((lane & 15) == 0)
                    redbuf[w][mt * 16 + qrow + r] = p;
            }
        __syncthreads();
        if (tid < 64) {
            float s = 0.f;
#pragma unroll
            for (int ww = 0; ww < 8; ++ww) s += redbuf[ww][tid];
            scores[trow0 + tid] = s;
        }
        // next tile's first LDS write targets Abuf (not redbuf) and is
        // followed by a barrier before any read -> no extra sync needed here
    }
}

// ---------------------------------------------------------------------------
// Kernel 3: softmax over T per batch row (fp32), 512 threads
// ---------------------------------------------------------------------------
__global__ void softmax_kernel(const float* __restrict__ scores, float* __restrict__ out) {
    int b   = blockIdx.x;
    int tid = threadIdx.x;               // 512
    const float* s = scores + b * Tv;
    float local[4];
    float m = -1e30f;
#pragma unroll
    for (int i = 0; i < 4; ++i) { local[i] = s[tid + i * 512]; m = fmaxf(m, local[i]); }
    __shared__ float red[8];
    int lane = tid & 63, w = tid >> 6;
#pragma unroll
    for (int x = 1; x < 64; x <<= 1) m = fmaxf(m, __shfl_xor(m, x));
    if (lane == 0) red[w] = m;
    __syncthreads();
#pragma unroll
    for (int ww = 0; ww < 8; ++ww) m = fmaxf(m, red[ww]);
    float sum = 0.f;
#pragma unroll
    for (int i = 0; i < 4; ++i) { local[i] = __expf(local[i] - m); sum += local[i]; }
#pragma unroll
    for (int x = 1; x < 64; x <<= 1) sum += __shfl_xor(sum, x);
    __syncthreads();
    if (lane == 0) red[w] = sum;
    __syncthreads();
    sum = 0.f;
#pragma unroll
    for (int ww = 0; ww < 8; ++ww) sum += red[ww];
    float inv = 1.0f / sum;
#pragma unroll
    for (int i = 0; i < 4; ++i) out[b * Tv + tid + i * 512] = local[i] * inv;
}

// ---------------------------------------------------------------------------
extern "C" void kernel_launch(void* const* d_in, const int* in_sizes, int n_in,
                              void* d_out, int out_size, void* d_ws, size_t ws_size,
                              hipStream_t stream) {
    const float* hidden = (const float*)d_in[0];   // (32, 1024)
    const float* enc    = (const float*)d_in[1];   // (32, 2048, 1024)
    const float* W      = (const float*)d_in[2];   // (512, 2048)
    const float* b_attn = (const float*)d_in[3];   // (512,)
    const float* v      = (const float*)d_in[4];   // (512,)
    float* out = (float*)d_out;                    // (32, 1, 2048) fp32

    char* ws = (char*)d_ws;
    bf16x8* We_sw = (bf16x8*)ws;                          // 1 MB
    float*  hp    = (float*)(ws + (1 << 20));             // 64 KB
    float*  sc    = (float*)(ws + (1 << 20) + (1 << 16)); // 256 KB

    prep_kernel<<<Hv, 256, 0, stream>>>(hidden, W, b_attn, We_sw, hp);
    attn_main<<<(Bv * Tv) / 256, 512, 0, stream>>>(enc, We_sw, hp, v, sc);
    softmax_kernel<<<Bv, 512, 0, stream>>>(sc, out);
}

// Round 2
// 458.153 us; speedup vs baseline: 1.4042x; 1.4042x over previous
//
#include <hip/hip_runtime.h>

// Problem constants
#define Bv 32
#define Tv 2048
#define Hv 512
#define Dv 1024

using bf16x8 = __attribute__((ext_vector_type(8))) __bf16;
using bf16x4 = __attribute__((ext_vector_type(4))) __bf16;
using f32x4  = __attribute__((ext_vector_type(4))) float;

// ---------------------------------------------------------------------------
// Kernel 1 (fused prep): one block per h row.
//  (a) We = W_attn[h, D:2D] -> bf16 MFMA B-fragment order (threads 0..127)
//  (b) hp[b][h] = hidden[b,:] . W_attn[h,0:D] + b_attn[h]   (all 256 threads)
// ---------------------------------------------------------------------------
__global__ void prep_kernel(const float* __restrict__ hidden,
                            const float* __restrict__ W,
                            const float* __restrict__ b_attn,
                            bf16x8* __restrict__ We_sw,
                            float* __restrict__ hp) {
    int h   = blockIdx.x;            // 0..511
    int tid = threadIdx.x;           // 256

    // --- (a) swizzle We row h ---
    if (tid < 128) {
        int d = tid * 8;
        const float* src = W + h * (2 * Dv) + Dv + d;
        float4 f0 = *(const float4*)src;
        float4 f1 = *(const float4*)(src + 4);
        bf16x8 o;
        o[0] = (__bf16)f0.x; o[1] = (__bf16)f0.y; o[2] = (__bf16)f0.z; o[3] = (__bf16)f0.w;
        o[4] = (__bf16)f1.x; o[5] = (__bf16)f1.y; o[6] = (__bf16)f1.z; o[7] = (__bf16)f1.w;
        int s = ((h >> 4) * 32 + (d >> 5)) * 64 + (((d >> 3) & 3) << 4) + (h & 15);
        We_sw[s] = o;
    }

    // --- (b) hid_proj ---
    float4 wh = ((const float4*)(W + h * (2 * Dv)))[tid];
    __shared__ float red[4][Bv];
    int lane = tid & 63, w = tid >> 6;
    for (int b = 0; b < Bv; ++b) {
        float4 x = ((const float4*)(hidden + b * Dv))[tid];
        float p = wh.x * x.x + wh.y * x.y + wh.z * x.z + wh.w * x.w;
#pragma unroll
        for (int m = 1; m < 64; m <<= 1) p += __shfl_xor(p, m);
        if (lane == 0) red[w][b] = p;
    }
    __syncthreads();
    if (tid < Bv)
        hp[tid * Hv + h] = red[0][tid] + red[1][tid] + red[2][tid] + red[3][tid] + b_attn[h];
}

__device__ __forceinline__ float fast_tanh(float x) {
    float xc = fminf(fmaxf(x, -9.0f), 9.0f);
    float e  = __expf(2.0f * xc);
    return 1.0f - 2.0f / (e + 1.0f);
}

// ---------------------------------------------------------------------------
// Kernel 2: scores[b,t] = sum_h v[h]*tanh( enc[b,t,:].We[h,:] + hp[b,h] )
// Grid 1024 x 512 threads: 64 rows x 512 h per block, 2 blocks/CU resident
// (VGPR-capped at 16 waves/CU) so barrier/latency stalls overlap across
// blocks. K-chunk = 128 floats -> 8 barriers per block (vs 16 in round-0).
//   - A(chunk+1) float4-loads issued before the barrier (latency under MFMA)
//   - B fragments rolling-prefetched one half-chunk (64 k) ahead
// LDS: row-major 64 x 136 bf16 (272 B row stride), double buffered,
// one barrier per chunk (write buf k, barrier, read buf k).
// ---------------------------------------------------------------------------
__global__ __launch_bounds__(512) void attn_main(
    const float* __restrict__ enc, const bf16x8* __restrict__ Bg,
    const float* __restrict__ hp, const float* __restrict__ vvec,
    float* __restrict__ scores)
{
    __shared__ __align__(16) __bf16 Abuf[2][64 * 136];  // 2 x 17408 B
    __shared__ float redbuf[8][64];

    const int tid  = threadIdx.x;
    const int lane = tid & 63;
    const int w    = tid >> 6;           // wave 0..7
    const int row0 = blockIdx.x * 64;
    const int batch = row0 >> 11;

    // --- A staging map: thread -> row = tid>>3, col segs (tid&7)*4 + s*32
    const int srow = tid >> 3;           // 0..63
    const int sd0  = (tid & 7) * 4;      // 0,4,..,28
    const float* gA = enc + (row0 + srow) * Dv + sd0;
    __bf16* lw0 = &Abuf[0][srow * 136 + sd0];

    // --- B fragment base: frag(j,kt) at Bg[((w*4+j)*32 + kt)*64 + lane]
    const bf16x8* Bptr = Bg + (w * 4 * 32) * 64 + lane;

    const int arow  = lane & 15;
    const int acol8 = (lane >> 4) * 8;

    // prologue: A(chunk0) and B(kt=0,1)
    float4 f[4];
#pragma unroll
    for (int s = 0; s < 4; ++s) f[s] = *(const float4*)(gA + s * 32);
    bf16x8 Bc[2][4];
#pragma unroll
    for (int ktl = 0; ktl < 2; ++ktl)
#pragma unroll
        for (int j = 0; j < 4; ++j)
            Bc[ktl][j] = Bptr[(j * 32 + ktl) * 64];

    f32x4 acc[4][4];
#pragma unroll
    for (int i = 0; i < 4; ++i)
#pragma unroll
        for (int j = 0; j < 4; ++j)
            acc[i][j] = (f32x4){0.f, 0.f, 0.f, 0.f};

    for (int kc = 0; kc < 8; ++kc) {
        // convert + store A(kc) into buf kc&1
        __bf16* p = lw0 + (kc & 1) * (64 * 136);
#pragma unroll
        for (int s = 0; s < 4; ++s) {
            bf16x4 o;
            o[0] = (__bf16)f[s].x; o[1] = (__bf16)f[s].y;
            o[2] = (__bf16)f[s].z; o[3] = (__bf16)f[s].w;
            *(bf16x4*)(p + s * 32) = o;
        }
        // issue A(kc+1) loads (full-chunk latency budget, hidden under MFMA)
        if (kc < 7) {
#pragma unroll
            for (int s = 0; s < 4; ++s)
                f[s] = *(const float4*)(gA + (kc + 1) * 128 + s * 32);
        }
        __syncthreads();

        const __bf16* rb = &Abuf[kc & 1][0];
#pragma unroll
        for (int hk = 0; hk < 2; ++hk) {
            // rolling B prefetch one half-chunk (64 k) ahead
            bf16x8 Bn[2][4];
            const int ktn = kc * 4 + (hk + 1) * 2;
            if (ktn < 32) {
#pragma unroll
                for (int ktl = 0; ktl < 2; ++ktl)
#pragma unroll
                    for (int j = 0; j < 4; ++j)
                        Bn[ktl][j] = Bptr[(j * 32 + ktn + ktl) * 64];
            }
#pragma unroll
            for (int ktl = 0; ktl < 2; ++ktl) {
                const int kofs = (hk * 2 + ktl) * 32;
                bf16x8 a0 = *(const bf16x8*)(rb + (0 * 16 + arow) * 136 + kofs + acol8);
                bf16x8 a1 = *(const bf16x8*)(rb + (1 * 16 + arow) * 136 + kofs + acol8);
                bf16x8 a2 = *(const bf16x8*)(rb + (2 * 16 + arow) * 136 + kofs + acol8);
                bf16x8 a3 = *(const bf16x8*)(rb + (3 * 16 + arow) * 136 + kofs + acol8);
#pragma unroll
                for (int j = 0; j < 4; ++j) {
                    acc[0][j] = __builtin_amdgcn_mfma_f32_16x16x32_bf16(a0, Bc[ktl][j], acc[0][j], 0, 0, 0);
                    acc[1][j] = __builtin_amdgcn_mfma_f32_16x16x32_bf16(a1, Bc[ktl][j], acc[1][j], 0, 0, 0);
                    acc[2][j] = __builtin_amdgcn_mfma_f32_16x16x32_bf16(a2, Bc[ktl][j], acc[2][j], 0, 0, 0);
                    acc[3][j] = __builtin_amdgcn_mfma_f32_16x16x32_bf16(a3, Bc[ktl][j], acc[3][j], 0, 0, 0);
                }
            }
            if (ktn < 32) {
#pragma unroll
                for (int ktl = 0; ktl < 2; ++ktl)
#pragma unroll
                    for (int j = 0; j < 4; ++j)
                        Bc[ktl][j] = Bn[ktl][j];
            }
        }
    }

    // Epilogue. C/D layout: col = lane&15, row = (lane>>4)*4 + reg
    float hpv[4], vv[4];
#pragma unroll
    for (int j = 0; j < 4; ++j) {
        int n  = w * 64 + j * 16 + (lane & 15);
        hpv[j] = hp[batch * Hv + n];
        vv[j]  = vvec[n];
    }
    const int qrow = (lane >> 4) * 4;
#pragma unroll
    for (int mt = 0; mt < 4; ++mt)
#pragma unroll
        for (int r = 0; r < 4; ++r) {
            float p = 0.f;
#pragma unroll
            for (int j = 0; j < 4; ++j)
                p += vv[j] * fast_tanh(acc[mt][j][r] + hpv[j]);
            p += __shfl_xor(p, 1);
            p += __shfl_xor(p, 2);
            p += __shfl_xor(p, 4);
            p += __shfl_xor(p, 8);
            if ((lane & 15) == 0)
                redbuf[w][mt * 16 + qrow + r] = p;
        }
    __syncthreads();
    if (tid < 64) {
        float s = 0.f;
#pragma unroll
        for (int ww = 0; ww < 8; ++ww) s += redbuf[ww][tid];
        scores[row0 + tid] = s;
    }
}

// ---------------------------------------------------------------------------
// Kernel 3: softmax over T per batch row (fp32), 512 threads
// ---------------------------------------------------------------------------
__global__ void softmax_kernel(const float* __restrict__ scores, float* __restrict__ out) {
    int b   = blockIdx.x;
    int tid = threadIdx.x;               // 512
    const float* s = scores + b * Tv;
    float local[4];
    float m = -1e30f;
#pragma unroll
    for (int i = 0; i < 4; ++i) { local[i] = s[tid + i * 512]; m = fmaxf(m, local[i]); }
    __shared__ float red[8];
    int lane = tid & 63, w = tid >> 6;
#pragma unroll
    for (int x = 1; x < 64; x <<= 1) m = fmaxf(m, __shfl_xor(m, x));
    if (lane == 0) red[w] = m;
    __syncthreads();
#pragma unroll
    for (int ww = 0; ww < 8; ++ww) m = fmaxf(m, red[ww]);
    float sum = 0.f;
#pragma unroll
    for (int i = 0; i < 4; ++i) { local[i] = __expf(local[i] - m); sum += local[i]; }
#pragma unroll
    for (int x = 1; x < 64; x <<= 1) sum += __shfl_xor(sum, x);
    __syncthreads();
    if (lane == 0) red[w] = sum;
    __syncthreads();
    sum = 0.f;
#pragma unroll
    for (int ww = 0; ww < 8; ++ww) sum += red[ww];
    float inv = 1.0f / sum;
#pragma unroll
    for (int i = 0; i < 4; ++i) out[b * Tv + tid + i * 512] = local[i] * inv;
}

// ---------------------------------------------------------------------------
extern "C" void kernel_launch(void* const* d_in, const int* in_sizes, int n_in,
                              void* d_out, int out_size, void* d_ws, size_t ws_size,
                              hipStream_t stream) {
    const float* hidden = (const float*)d_in[0];   // (32, 1024)
    const float* enc    = (const float*)d_in[1];   // (32, 2048, 1024)
    const float* W      = (const float*)d_in[2];   // (512, 2048)
    const float* b_attn = (const float*)d_in[3];   // (512,)
    const float* v      = (const float*)d_in[4];   // (512,)
    float* out = (float*)d_out;                    // (32, 1, 2048) fp32

    char* ws = (char*)d_ws;
    bf16x8* We_sw = (bf16x8*)ws;                          // 1 MB
    float*  hp    = (float*)(ws + (1 << 20));             // 64 KB
    float*  sc    = (float*)(ws + (1 << 20) + (1 << 16)); // 256 KB

    prep_kernel<<<Hv, 256, 0, stream>>>(hidden, W, b_attn, We_sw, hp);
    attn_main<<<(Bv * Tv) / 64, 512, 0, stream>>>(enc, We_sw, hp, v, sc);
    softmax_kernel<<<Bv, 512, 0, stream>>>(sc, out);
}

// Round 4
// 453.886 us; speedup vs baseline: 1.4174x; 1.0094x over previous
//
#include <hip/hip_runtime.h>

// Problem constants
#define Bv 32
#define Tv 2048
#define Hv 512
#define Dv 1024

using bf16x8 = __attribute__((ext_vector_type(8))) __bf16;
using bf16x4 = __attribute__((ext_vector_type(4))) __bf16;
using f32x4  = __attribute__((ext_vector_type(4))) float;

// ---------------------------------------------------------------------------
// Kernel 1 (fused prep): one block per h row.
//  (a) We = W_attn[h, D:2D] -> bf16 MFMA B-fragment order (threads 0..127)
//  (b) hp[b][h] = hidden[b,:] . W_attn[h,0:D] + b_attn[h]   (all 256 threads)
// ---------------------------------------------------------------------------
__global__ void prep_kernel(const float* __restrict__ hidden,
                            const float* __restrict__ W,
                            const float* __restrict__ b_attn,
                            bf16x8* __restrict__ We_sw,
                            float* __restrict__ hp) {
    int h   = blockIdx.x;            // 0..511
    int tid = threadIdx.x;           // 256

    // --- (a) swizzle We row h ---
    if (tid < 128) {
        int d = tid * 8;
        const float* src = W + h * (2 * Dv) + Dv + d;
        float4 f0 = *(const float4*)src;
        float4 f1 = *(const float4*)(src + 4);
        bf16x8 o;
        o[0] = (__bf16)f0.x; o[1] = (__bf16)f0.y; o[2] = (__bf16)f0.z; o[3] = (__bf16)f0.w;
        o[4] = (__bf16)f1.x; o[5] = (__bf16)f1.y; o[6] = (__bf16)f1.z; o[7] = (__bf16)f1.w;
        int s = ((h >> 4) * 32 + (d >> 5)) * 64 + (((d >> 3) & 3) << 4) + (h & 15);
        We_sw[s] = o;
    }

    // --- (b) hid_proj ---
    float4 wh = ((const float4*)(W + h * (2 * Dv)))[tid];
    __shared__ float red[4][Bv];
    int lane = tid & 63, w = tid >> 6;
    for (int b = 0; b < Bv; ++b) {
        float4 x = ((const float4*)(hidden + b * Dv))[tid];
        float p = wh.x * x.x + wh.y * x.y + wh.z * x.z + wh.w * x.w;
#pragma unroll
        for (int m = 1; m < 64; m <<= 1) p += __shfl_xor(p, m);
        if (lane == 0) red[w][b] = p;
    }
    __syncthreads();
    if (tid < Bv)
        hp[tid * Hv + h] = red[0][tid] + red[1][tid] + red[2][tid] + red[3][tid] + b_attn[h];
}

__device__ __forceinline__ float fast_tanh(float x) {
    float xc = fminf(fmaxf(x, -9.0f), 9.0f);
    float e  = __expf(2.0f * xc);
    return 1.0f - 2.0f / (e + 1.0f);
}

// ---------------------------------------------------------------------------
// Kernel 2: scores[b,t] = sum_h v[h]*tanh( enc[b,t,:].We[h,:] + hp[b,h] )
// Grid 1024 x 512 threads: 64 rows x 512 h per block, 2 blocks/CU resident.
// Round-0 schedule (chunk = 64 floats, 16 chunks, full-chunk-ahead B
// prefetch) BUT with the __syncthreads vmcnt(0) drain removed: per-chunk
// barrier = s_waitcnt lgkmcnt(0) (LDS-write visibility only) + raw
// s_barrier, sched_barrier(0)-pinned. Register-destined global loads (A
// float4 prefetch, B fragments) stay in flight across the barrier; only
// LDS traffic needs cross-wave ordering. s_setprio(1) around MFMA clusters.
// ---------------------------------------------------------------------------
__global__ __launch_bounds__(512) void attn_main(
    const float* __restrict__ enc, const bf16x8* __restrict__ Bg,
    const float* __restrict__ hp, const float* __restrict__ vvec,
    float* __restrict__ scores)
{
    __shared__ __align__(16) __bf16 Abuf[2][64 * 72];  // 2 x 9216 B
    __shared__ float redbuf[8][64];

    const int tid   = threadIdx.x;
    const int lane  = tid & 63;
    const int w     = tid >> 6;          // wave 0..7
    const int row0  = blockIdx.x * 64;
    const int batch = row0 >> 11;

    // --- A staging map (coalesced): thread -> row = tid>>3, d segs (tid&7)*4, +32
    const int srow = tid >> 3;           // 0..63
    const int sd0  = (tid & 7) * 4;      // 0,4,..,28
    const float* gA = enc + (row0 + srow) * Dv + sd0;
    __bf16* lw0 = &Abuf[0][srow * 72 + sd0];

    // --- B fragment base: frag(j,kt) at Bg[((w*4+j)*32 + kt)*64 + lane]
    const bf16x8* Bptr = Bg + (w * 4 * 32) * 64 + lane;

    f32x4 acc[4][4];
#pragma unroll
    for (int i = 0; i < 4; ++i)
#pragma unroll
        for (int j = 0; j < 4; ++j)
            acc[i][j] = (f32x4){0.f, 0.f, 0.f, 0.f};

    // prologue: A(0) and B(0) prefetch
    float4 f0 = *(const float4*)gA;
    float4 f1 = *(const float4*)(gA + 32);
    bf16x8 Bc[2][4];
#pragma unroll
    for (int ktl = 0; ktl < 2; ++ktl)
#pragma unroll
        for (int j = 0; j < 4; ++j)
            Bc[ktl][j] = Bptr[(j * 32 + ktl) * 64];

    const int arow  = lane & 15;
    const int acol8 = (lane >> 4) * 8;

    for (int kc = 0; kc < 16; ++kc) {
        // convert + store A(kc) into buf kc&1 (conflict-free ds_write_b64 x2)
        __bf16* p = lw0 + (kc & 1) * (64 * 72);
        bf16x4 o0, o1;
        o0[0] = (__bf16)f0.x; o0[1] = (__bf16)f0.y; o0[2] = (__bf16)f0.z; o0[3] = (__bf16)f0.w;
        o1[0] = (__bf16)f1.x; o1[1] = (__bf16)f1.y; o1[2] = (__bf16)f1.z; o1[3] = (__bf16)f1.w;
        *(bf16x4*)p        = o0;
        *(bf16x4*)(p + 32) = o1;
        // issue A(kc+1) (full-chunk latency budget; NOT drained at barrier)
        if (kc < 15) {
            f0 = *(const float4*)(gA + (kc + 1) * 64);
            f1 = *(const float4*)(gA + (kc + 1) * 64 + 32);
        }
        // barrier WITHOUT vmcnt drain: only LDS writes need visibility
        __builtin_amdgcn_sched_barrier(0);
        asm volatile("s_waitcnt lgkmcnt(0)" ::: "memory");
        __builtin_amdgcn_s_barrier();
        __builtin_amdgcn_sched_barrier(0);

        // issue B(kc+1) prefetch (in flight across next barrier too)
        bf16x8 Bn[2][4];
        if (kc < 15) {
#pragma unroll
            for (int ktl = 0; ktl < 2; ++ktl)
#pragma unroll
                for (int j = 0; j < 4; ++j)
                    Bn[ktl][j] = Bptr[(j * 32 + (kc + 1) * 2 + ktl) * 64];
        }

        const __bf16* rb = &Abuf[kc & 1][0];
#pragma unroll
        for (int ktl = 0; ktl < 2; ++ktl) {
            bf16x8 a0 = *(const bf16x8*)(rb + (0 * 16 + arow) * 72 + ktl * 32 + acol8);
            bf16x8 a1 = *(const bf16x8*)(rb + (1 * 16 + arow) * 72 + ktl * 32 + acol8);
            bf16x8 a2 = *(const bf16x8*)(rb + (2 * 16 + arow) * 72 + ktl * 32 + acol8);
            bf16x8 a3 = *(const bf16x8*)(rb + (3 * 16 + arow) * 72 + ktl * 32 + acol8);
            __builtin_amdgcn_s_setprio(1);
#pragma unroll
            for (int j = 0; j < 4; ++j) {
                acc[0][j] = __builtin_amdgcn_mfma_f32_16x16x32_bf16(a0, Bc[ktl][j], acc[0][j], 0, 0, 0);
                acc[1][j] = __builtin_amdgcn_mfma_f32_16x16x32_bf16(a1, Bc[ktl][j], acc[1][j], 0, 0, 0);
                acc[2][j] = __builtin_amdgcn_mfma_f32_16x16x32_bf16(a2, Bc[ktl][j], acc[2][j], 0, 0, 0);
                acc[3][j] = __builtin_amdgcn_mfma_f32_16x16x32_bf16(a3, Bc[ktl][j], acc[3][j], 0, 0, 0);
            }
            __builtin_amdgcn_s_setprio(0);
        }
#pragma unroll
        for (int ktl = 0; ktl < 2; ++ktl)
#pragma unroll
            for (int j = 0; j < 4; ++j)
                Bc[ktl][j] = Bn[ktl][j];
    }

    // Epilogue. C/D layout: col = lane&15, row = (lane>>4)*4 + reg
    float hpv[4], vv[4];
#pragma unroll
    for (int j = 0; j < 4; ++j) {
        int n  = w * 64 + j * 16 + (lane & 15);
        hpv[j] = hp[batch * Hv + n];
        vv[j]  = vvec[n];
    }
    const int qrow = (lane >> 4) * 4;
#pragma unroll
    for (int mt = 0; mt < 4; ++mt)
#pragma unroll
        for (int r = 0; r < 4; ++r) {
            float p = 0.f;
#pragma unroll
            for (int j = 0; j < 4; ++j)
                p += vv[j] * fast_tanh(acc[mt][j][r] + hpv[j]);
            p += __shfl_xor(p, 1);
            p += __shfl_xor(p, 2);
            p += __shfl_xor(p, 4);
            p += __shfl_xor(p, 8);
            if ((lane & 15) == 0)
                redbuf[w][mt * 16 + qrow + r] = p;
        }
    __syncthreads();
    if (tid < 64) {
        float s = 0.f;
#pragma unroll
        for (int ww = 0; ww < 8; ++ww) s += redbuf[ww][tid];
        scores[row0 + tid] = s;
    }
}

// ---------------------------------------------------------------------------
// Kernel 3: softmax over T per batch row (fp32), 512 threads
// ---------------------------------------------------------------------------
__global__ void softmax_kernel(const float* __restrict__ scores, float* __restrict__ out) {
    int b   = blockIdx.x;
    int tid = threadIdx.x;               // 512
    const float* s = scores + b * Tv;
    float local[4];
    float m = -1e30f;
#pragma unroll
    for (int i = 0; i < 4; ++i) { local[i] = s[tid + i * 512]; m = fmaxf(m, local[i]); }
    __shared__ float red[8];
    int lane = tid & 63, w = tid >> 6;
#pragma unroll
    for (int x = 1; x < 64; x <<= 1) m = fmaxf(m, __shfl_xor(m, x));
    if (lane == 0) red[w] = m;
    __syncthreads();
#pragma unroll
    for (int ww = 0; ww < 8; ++ww) m = fmaxf(m, red[ww]);
    float sum = 0.f;
#pragma unroll
    for (int i = 0; i < 4; ++i) { local[i] = __expf(local[i] - m); sum += local[i]; }
#pragma unroll
    for (int x = 1; x < 64; x <<= 1) sum += __shfl_xor(sum, x);
    __syncthreads();
    if (lane == 0) red[w] = sum;
    __syncthreads();
    sum = 0.f;
#pragma unroll
    for (int ww = 0; ww < 8; ++ww) sum += red[ww];
    float inv = 1.0f / sum;
#pragma unroll
    for (int i = 0; i < 4; ++i) out[b * Tv + tid + i * 512] = local[i] * inv;
}

// ---------------------------------------------------------------------------
extern "C" void kernel_launch(void* const* d_in, const int* in_sizes, int n_in,
                              void* d_out, int out_size, void* d_ws, size_t ws_size,
                              hipStream_t stream) {
    const float* hidden = (const float*)d_in[0];   // (32, 1024)
    const float* enc    = (const float*)d_in[1];   // (32, 2048, 1024)
    const float* W      = (const float*)d_in[2];   // (512, 2048)
    const float* b_attn = (const float*)d_in[3];   // (512,)
    const float* v      = (const float*)d_in[4];   // (512,)
    float* out = (float*)d_out;                    // (32, 1, 2048) fp32

    char* ws = (char*)d_ws;
    bf16x8* We_sw = (bf16x8*)ws;                          // 1 MB
    float*  hp    = (float*)(ws + (1 << 20));             // 64 KB
    float*  sc    = (float*)(ws + (1 << 20) + (1 << 16)); // 256 KB

    prep_kernel<<<Hv, 256, 0, stream>>>(hidden, W, b_attn, We_sw, hp);
    attn_main<<<(Bv * Tv) / 64, 512, 0, stream>>>(enc, We_sw, hp, v, sc);
    softmax_kernel<<<Bv, 512, 0, stream>>>(sc, out);
}